// Round 2
// baseline (243.713 us; speedup 1.0000x reference)
//
#include <hip/hip_runtime.h>
#include <hip/hip_bf16.h>

// ---------------------------------------------------------------------------
// Fused: h = rmsnorm(x@W0+b0); h = sigmoid(h@W1+b1)+h; out = relu(h@W2+b2)+h
// M=32768 rows, D=1024, H=128.
// Reference dtype is fp32; round-1 NaN suggests inputs ARE fp32 (bf16 misread
// of fp32 bits -> NaN). This round hedges: device-side dtype detect + both
// bf16/fp32 fused variants (wrong one early-exits on a ws flag).
// Staging: plain global load -> cvt -> ds_write_b128 (no global_load_lds),
// single-buffer LDS, register preload pipeline. XOR-swizzled LDS chunks.
// ---------------------------------------------------------------------------

using u16    = unsigned short;
using f32x4  = __attribute__((ext_vector_type(4))) float;
using bf16x8 = __attribute__((ext_vector_type(8))) short;   // 8 bf16 = 4 VGPRs
using u16x8  = __attribute__((ext_vector_type(8))) unsigned short;

__device__ __forceinline__ float bf2f(u16 u) {
  union { unsigned int i; float f; } v; v.i = ((unsigned int)u) << 16; return v.f;
}
__device__ __forceinline__ u16 f2bf(float f) {
  union { float f; unsigned int i; } v; v.f = f;
  unsigned int r = v.i + 0x7fffu + ((v.i >> 16) & 1u);   // RNE
  return (u16)(r >> 16);
}

// ws layout (byte offsets): flag int @0; W0T bf16[128][1024] @64;
// W1T bf16[128][128] @262208; W2T @294976; biases fp32[3][128] @327744.
#define WS_W0T 64
#define WS_W1T 262208
#define WS_W2T 294976
#define WS_BIAS 327744

// swizzled byte offset into [128 rows][16 chunks of 8 bf16] tile (256B/row)
__device__ __forceinline__ int hoff(int row, int col) {
  return row * 256 + (((col >> 3) ^ (row & 7)) << 4) + ((col & 7) << 1);
}

// ---------------------------------------------------------------------------
__global__ void detect_kernel(const u16* __restrict__ x, int* __restrict__ flag) {
  if (threadIdx.x == 0 && blockIdx.x == 0) {
    int hits = 0;
    for (int i = 0; i < 512; ++i) {
      int e = (x[i] >> 7) & 0xFF;          // bf16 exponent field
      hits += (e >= 0xC8);                 // |v| >= 2^73 -> not sane bf16 data
    }
    *flag = (hits > 8) ? 0 : 1;            // 1 = bf16 inputs, 0 = fp32 inputs
  }
}

// ---------------------------------------------------------------------------
// prep: W0(1024x128)->W0T bf16, W1/W2(128x128)->W1T/W2T bf16, biases->fp32.
// blocks 0..127 W0, 128..143 W1, 144..159 W2, 160 biases. Branches on flag.
// ---------------------------------------------------------------------------
__global__ void __launch_bounds__(256)
prep_kernel(const void* __restrict__ W0, const void* __restrict__ W1,
            const void* __restrict__ W2, const void* __restrict__ b0,
            const void* __restrict__ b1, const void* __restrict__ b2,
            char* __restrict__ wsb) {
  const int isbf = *(const int*)wsb;
  const int bid = blockIdx.x;
  if (bid == 160) {
    float* bias = (float*)(wsb + WS_BIAS);
    for (int i = threadIdx.x; i < 384; i += 256) {
      int which = i >> 7, j = i & 127;
      const void* src = (which == 0) ? b0 : (which == 1) ? b1 : b2;
      bias[i] = isbf ? bf2f(((const u16*)src)[j]) : ((const float*)src)[j];
    }
    return;
  }
  __shared__ float tile[32][33];
  const void* src; u16* dst; int K, N, kt, nt;
  if (bid < 128)      { src = W0; dst = (u16*)(wsb + WS_W0T); K = 1024; N = 128; kt = bid >> 2;         nt = bid & 3; }
  else if (bid < 144) { src = W1; dst = (u16*)(wsb + WS_W1T); K = 128;  N = 128; kt = (bid - 128) >> 2; nt = (bid - 128) & 3; }
  else                { src = W2; dst = (u16*)(wsb + WS_W2T); K = 128;  N = 128; kt = (bid - 144) >> 2; nt = (bid - 144) & 3; }
  const int tx = threadIdx.x & 31, ty = threadIdx.x >> 5;
#pragma unroll
  for (int i = 0; i < 4; ++i) {
    int k = kt * 32 + ty + i * 8, n = nt * 32 + tx;
    size_t idx = (size_t)k * N + n;
    tile[ty + i * 8][tx] = isbf ? bf2f(((const u16*)src)[idx]) : ((const float*)src)[idx];
  }
  __syncthreads();
#pragma unroll
  for (int i = 0; i < 4; ++i) {
    int n = nt * 32 + ty + i * 8, k = kt * 32 + tx;
    dst[(size_t)n * K + k] = f2bf(tile[tx][ty + i * 8]);
  }
}

// ---------------------------------------------------------------------------
template <bool BF>
__global__ void __launch_bounds__(512)
fused_kernel(const void* __restrict__ xin, const char* __restrict__ wsb,
             void* __restrict__ outv) {
  if (*(const int*)wsb != (BF ? 1 : 0)) return;   // wrong-dtype variant: exit

  __shared__ char smem[65536];
  char* xs  = smem;           // GEMM0 x-slab  [128r][8 chunks]*16B = 16KB
  char* wsm = smem + 16384;   // GEMM0 w-slab  16KB
  char* hns = smem;           // after GEMM0: [128][128] bf16 swizzled, 32KB
  char* h1s = smem + 32768;   // 32KB (untouched by GEMM0)

  const u16* w0t   = (const u16*)(wsb + WS_W0T);
  const u16* w1t   = (const u16*)(wsb + WS_W1T);
  const u16* w2t   = (const u16*)(wsb + WS_W2T);
  const float* bias = (const float*)(wsb + WS_BIAS);

  const int tid    = threadIdx.x;
  const int lane   = tid & 63;
  const int wave   = tid >> 6;
  const int lane16 = lane & 15;
  const int quad   = lane >> 4;
  const int m_base = (wave & 3) * 32;
  const int n_base = (wave >> 2) * 64;
  const int row0   = blockIdx.x * 128;

  float b0v[4], b1v[4], b2v[4];
#pragma unroll
  for (int nt = 0; nt < 4; ++nt) {
    int col = n_base + nt * 16 + lane16;
    b0v[nt] = bias[col]; b1v[nt] = bias[128 + col]; b2v[nt] = bias[256 + col];
  }

  // staging assignment: thread owns chunks tid and tid+512 (of 1024);
  // chunk s -> row r=s>>3, logical chunk c=s&7.
  const int r0 = tid >> 3, c0 = tid & 7, r1 = r0 + 64;

  u16x8 sx[2], sw[2];
  auto preload = [&](int k0) {
#pragma unroll
    for (int i = 0; i < 2; ++i) {
      int r = (i == 0) ? r0 : r1;
      size_t eoff = (size_t)(row0 + r) * 1024 + k0 + c0 * 8;
      if (BF) {
        sx[i] = *(const u16x8*)((const u16*)xin + eoff);
      } else {
        const float* p = (const float*)xin + eoff;
        f32x4 f0 = *(const f32x4*)p;
        f32x4 f1 = *(const f32x4*)(p + 4);
        u16x8 t;
#pragma unroll
        for (int e = 0; e < 4; ++e) { t[e] = f2bf(f0[e]); t[e + 4] = f2bf(f1[e]); }
        sx[i] = t;
      }
      sw[i] = *(const u16x8*)(w0t + (size_t)r * 1024 + k0 + c0 * 8);
    }
  };

  f32x4 acc[2][4] = {};
  preload(0);

  // ---- GEMM0: h = x @ W0, K=1024, 16 slabs of BK=64, single-buffer ----
  for (int s = 0; s < 16; ++s) {
    __syncthreads();                       // prev slab fully consumed
#pragma unroll
    for (int i = 0; i < 2; ++i) {
      int r = (i == 0) ? r0 : r1;
      int p = c0 ^ (r & 7);                // physical chunk (swizzle)
      *(u16x8*)(xs  + r * 128 + p * 16) = sx[i];
      *(u16x8*)(wsm + r * 128 + p * 16) = sw[i];
    }
    __syncthreads();                       // slab s visible
    if (s < 15) preload((s + 1) * 64);     // overlap with MFMA below
#pragma unroll
    for (int kk = 0; kk < 2; ++kk) {
      int ph = ((kk * 4 + quad) ^ (lane & 7)) << 4;
      bf16x8 a[2], b[4];
#pragma unroll
      for (int rh = 0; rh < 2; ++rh)
        a[rh] = *(const bf16x8*)(xs + (m_base + rh * 16 + lane16) * 128 + ph);
#pragma unroll
      for (int nt = 0; nt < 4; ++nt)
        b[nt] = *(const bf16x8*)(wsm + (n_base + nt * 16 + lane16) * 128 + ph);
#pragma unroll
      for (int rh = 0; rh < 2; ++rh)
#pragma unroll
        for (int nt = 0; nt < 4; ++nt)
          acc[rh][nt] = __builtin_amdgcn_mfma_f32_16x16x32_bf16(
              a[rh], b[nt], acc[rh][nt], 0, 0, 0);
    }
  }
  __syncthreads();

  // ---- scatter h+b0 -> hns (C-layout: col=lane16, row=quad*4+reg) ----
#pragma unroll
  for (int rh = 0; rh < 2; ++rh)
#pragma unroll
    for (int nt = 0; nt < 4; ++nt) {
      int col = n_base + nt * 16 + lane16;
#pragma unroll
      for (int r = 0; r < 4; ++r) {
        int row = m_base + rh * 16 + quad * 4 + r;
        *(u16*)(hns + hoff(row, col)) = f2bf(acc[rh][nt][r] + b0v[nt]);
      }
    }
  __syncthreads();

  // ---- rmsnorm over H=128: 4 threads/row ----
  {
    int r = tid >> 2, qq = tid & 3;
    u16x8 vals[4];
    float ss = 0.f;
#pragma unroll
    for (int j = 0; j < 4; ++j) {
      int c = qq * 4 + j;
      vals[j] = *(const u16x8*)(hns + r * 256 + ((c ^ (r & 7)) << 4));
#pragma unroll
      for (int e = 0; e < 8; ++e) { float f = bf2f(vals[j][e]); ss += f * f; }
    }
    ss += __shfl_xor(ss, 1);
    ss += __shfl_xor(ss, 2);
    float scale = rsqrtf(ss * (1.f / 128.f) + 1e-6f);
#pragma unroll
    for (int j = 0; j < 4; ++j) {
      u16x8 o;
#pragma unroll
      for (int e = 0; e < 8; ++e) o[e] = f2bf(bf2f(vals[j][e]) * scale);
      int c = qq * 4 + j;
      *(u16x8*)(hns + r * 256 + ((c ^ (r & 7)) << 4)) = o;
    }
  }
  __syncthreads();

  // ---- GEMM1: h1 = sigmoid(hn @ W1 + b1) + hn -> h1s ----
  f32x4 acc1[2][4] = {};
#pragma unroll
  for (int kk = 0; kk < 4; ++kk) {
    int ph = ((kk * 4 + quad) ^ (lane & 7)) << 4;
    bf16x8 a[2], b[4];
#pragma unroll
    for (int rh = 0; rh < 2; ++rh)
      a[rh] = *(const bf16x8*)(hns + (m_base + rh * 16 + lane16) * 256 + ph);
#pragma unroll
    for (int nt = 0; nt < 4; ++nt)
      b[nt] = *(const bf16x8*)(w1t + (size_t)(n_base + nt * 16 + lane16) * 128 +
                               kk * 32 + quad * 8);
#pragma unroll
    for (int rh = 0; rh < 2; ++rh)
#pragma unroll
      for (int nt = 0; nt < 4; ++nt)
        acc1[rh][nt] = __builtin_amdgcn_mfma_f32_16x16x32_bf16(
            a[rh], b[nt], acc1[rh][nt], 0, 0, 0);
  }
#pragma unroll
  for (int rh = 0; rh < 2; ++rh)
#pragma unroll
    for (int nt = 0; nt < 4; ++nt) {
      int col = n_base + nt * 16 + lane16;
#pragma unroll
      for (int r = 0; r < 4; ++r) {
        int row = m_base + rh * 16 + quad * 4 + r;
        int o = hoff(row, col);
        float hn = bf2f(*(const u16*)(hns + o));
        float v = acc1[rh][nt][r] + b1v[nt];
        *(u16*)(h1s + o) = f2bf(hn + 1.f / (1.f + __expf(-v)));
      }
    }
  __syncthreads();

  // ---- GEMM2: out = relu(h1 @ W2 + b2) + h1, fused store ----
  f32x4 acc2[2][4] = {};
#pragma unroll
  for (int kk = 0; kk < 4; ++kk) {
    int ph = ((kk * 4 + quad) ^ (lane & 7)) << 4;
    bf16x8 a[2], b[4];
#pragma unroll
    for (int rh = 0; rh < 2; ++rh)
      a[rh] = *(const bf16x8*)(h1s + (m_base + rh * 16 + lane16) * 256 + ph);
#pragma unroll
    for (int nt = 0; nt < 4; ++nt)
      b[nt] = *(const bf16x8*)(w2t + (size_t)(n_base + nt * 16 + lane16) * 128 +
                               kk * 32 + quad * 8);
#pragma unroll
    for (int rh = 0; rh < 2; ++rh)
#pragma unroll
      for (int nt = 0; nt < 4; ++nt)
        acc2[rh][nt] = __builtin_amdgcn_mfma_f32_16x16x32_bf16(
            a[rh], b[nt], acc2[rh][nt], 0, 0, 0);
  }
#pragma unroll
  for (int rh = 0; rh < 2; ++rh)
#pragma unroll
    for (int nt = 0; nt < 4; ++nt) {
      int col = n_base + nt * 16 + lane16;
#pragma unroll
      for (int r = 0; r < 4; ++r) {
        int row = m_base + rh * 16 + quad * 4 + r;
        float h1v = bf2f(*(const u16*)(h1s + hoff(row, col)));
        float v = acc2[rh][nt][r] + b2v[nt];
        float res = h1v + fmaxf(v, 0.f);
        size_t oidx = (size_t)(row0 + row) * 128 + col;
        if (BF) ((u16*)outv)[oidx] = f2bf(res);
        else    ((float*)outv)[oidx] = res;
      }
    }
}

// ---------------------------------------------------------------------------
extern "C" void kernel_launch(void* const* d_in, const int* in_sizes, int n_in,
                              void* d_out, int out_size, void* d_ws, size_t ws_size,
                              hipStream_t stream) {
  const void* x  = d_in[0];
  const void* W0 = d_in[1];
  const void* b0 = d_in[2];
  const void* W1 = d_in[3];
  const void* b1 = d_in[4];
  const void* W2 = d_in[5];
  const void* b2 = d_in[6];
  char* wsb = (char*)d_ws;

  detect_kernel<<<1, 64, 0, stream>>>((const u16*)x, (int*)wsb);
  prep_kernel<<<161, 256, 0, stream>>>(W0, W1, W2, b0, b1, b2, wsb);
  fused_kernel<true><<<256, 512, 0, stream>>>(x, wsb, d_out);
  fused_kernel<false><<<256, 512, 0, stream>>>(x, wsb, d_out);
}

// Round 7
// 228.515 us; speedup vs baseline: 1.0665x; 1.0665x over previous
//
#include <hip/hip_runtime.h>
#include <hip/hip_bf16.h>

// ---------------------------------------------------------------------------
// Fused: h = rmsnorm(x@W0+b0); h = sigmoid(h@W1+b1)+h; out = relu(h@W2+b2)+h
// M=32768, D=1024, H=128.
// R7: INPUTS/OUTPUT ARE FP32 (re-attribution of R2's pass: the fp32 ghost
// variant did the work; FETCH=67MB was L3-masked fp32-x, WRITE=16.4MB is
// exactly fp32 out; all bf16-hardcoded rounds NaN'd from misread fp32 bits).
// This is R2's PASSING flag=0 path verbatim: prep converts fp32 W->bf16 WT
// (+fp32 biases) into ws; fused loads x fp32->bf16 in reg preload, computes
// bf16 MFMA w/ fp32 accum, stores fp32. No detect, no ghost. Zero other
// deltas vs the R2-verified code path.
// ---------------------------------------------------------------------------

using u16    = unsigned short;
using f32x4  = __attribute__((ext_vector_type(4))) float;
using bf16x8 = __attribute__((ext_vector_type(8))) short;   // 8 bf16 = 4 VGPRs
using u16x8  = __attribute__((ext_vector_type(8))) unsigned short;

__device__ __forceinline__ float bf2f(u16 u) {
  union { unsigned int i; float f; } v; v.i = ((unsigned int)u) << 16; return v.f;
}
__device__ __forceinline__ u16 f2bf(float f) {
  union { float f; unsigned int i; } v; v.f = f;
  unsigned int r = v.i + 0x7fffu + ((v.i >> 16) & 1u);   // RNE
  return (u16)(r >> 16);
}

// ws layout (byte offsets): [0,64) unused; W0T bf16[128][1024] @64;
// W1T bf16[128][128] @262208; W2T @294976; biases fp32[3][128] @327744.
#define WS_W0T 64
#define WS_W1T 262208
#define WS_W2T 294976
#define WS_BIAS 327744

// swizzled byte offset into [128 rows][16 chunks of 8 bf16] tile (256B/row)
__device__ __forceinline__ int hoff(int row, int col) {
  return row * 256 + (((col >> 3) ^ (row & 7)) << 4) + ((col & 7) << 1);
}

// ---------------------------------------------------------------------------
// prep: W0(1024x128) fp32 -> W0T bf16; W1/W2(128x128) fp32 -> W1T/W2T bf16;
// biases fp32 -> fp32. blocks 0..127 W0, 128..143 W1, 144..159 W2, 160 biases.
// (R2's prep, isbf=0 path hardcoded.)
// ---------------------------------------------------------------------------
__global__ void __launch_bounds__(256)
prep_kernel(const float* __restrict__ W0, const float* __restrict__ W1,
            const float* __restrict__ W2, const float* __restrict__ b0,
            const float* __restrict__ b1, const float* __restrict__ b2,
            char* __restrict__ wsb) {
  const int bid = blockIdx.x;
  if (bid == 160) {
    float* bias = (float*)(wsb + WS_BIAS);
    for (int i = threadIdx.x; i < 384; i += 256) {
      int which = i >> 7, j = i & 127;
      const float* src = (which == 0) ? b0 : (which == 1) ? b1 : b2;
      bias[i] = src[j];
    }
    return;
  }
  __shared__ float tile[32][33];
  const float* src; u16* dst; int K, N, kt, nt;
  if (bid < 128)      { src = W0; dst = (u16*)(wsb + WS_W0T); K = 1024; N = 128; kt = bid >> 2;         nt = bid & 3; }
  else if (bid < 144) { src = W1; dst = (u16*)(wsb + WS_W1T); K = 128;  N = 128; kt = (bid - 128) >> 2; nt = (bid - 128) & 3; }
  else                { src = W2; dst = (u16*)(wsb + WS_W2T); K = 128;  N = 128; kt = (bid - 144) >> 2; nt = (bid - 144) & 3; }
  const int tx = threadIdx.x & 31, ty = threadIdx.x >> 5;
#pragma unroll
  for (int i = 0; i < 4; ++i) {
    int k = kt * 32 + ty + i * 8, n = nt * 32 + tx;
    tile[ty + i * 8][tx] = src[(size_t)k * N + n];
  }
  __syncthreads();
#pragma unroll
  for (int i = 0; i < 4; ++i) {
    int n = nt * 32 + ty + i * 8, k = kt * 32 + tx;
    dst[(size_t)n * K + k] = f2bf(tile[tx][ty + i * 8]);
  }
}

// ---------------------------------------------------------------------------
// fused kernel — R2's fused_kernel<false> (the PASSING fp32 path) verbatim,
// flag check removed.
// ---------------------------------------------------------------------------
__global__ void __launch_bounds__(512)
fused_kernel(const float* __restrict__ xin, const char* __restrict__ wsb,
             float* __restrict__ outv) {
  __shared__ char smem[65536];
  char* xs  = smem;           // GEMM0 x-slab  [128r][8 chunks]*16B = 16KB
  char* wsm = smem + 16384;   // GEMM0 w-slab  16KB
  char* hns = smem;           // after GEMM0: [128][128] bf16 swizzled, 32KB
  char* h1s = smem + 32768;   // 32KB (untouched by GEMM0)

  const u16* w0t    = (const u16*)(wsb + WS_W0T);
  const u16* w1t    = (const u16*)(wsb + WS_W1T);
  const u16* w2t    = (const u16*)(wsb + WS_W2T);
  const float* bias = (const float*)(wsb + WS_BIAS);

  const int tid    = threadIdx.x;
  const int lane   = tid & 63;
  const int wave   = tid >> 6;
  const int lane16 = lane & 15;
  const int quad   = lane >> 4;
  const int m_base = (wave & 3) * 32;
  const int n_base = (wave >> 2) * 64;
  const int row0   = blockIdx.x * 128;

  float b0v[4], b1v[4], b2v[4];
#pragma unroll
  for (int nt = 0; nt < 4; ++nt) {
    int col = n_base + nt * 16 + lane16;
    b0v[nt] = bias[col]; b1v[nt] = bias[128 + col]; b2v[nt] = bias[256 + col];
  }

  // staging assignment: thread owns chunks tid and tid+512 (of 1024);
  // chunk s -> row r=s>>3, logical chunk c=s&7.
  const int r0 = tid >> 3, c0 = tid & 7, r1 = r0 + 64;

  u16x8 sx[2], sw[2];
  auto preload = [&](int k0) {
#pragma unroll
    for (int i = 0; i < 2; ++i) {
      int r = (i == 0) ? r0 : r1;
      size_t eoff = (size_t)(row0 + r) * 1024 + k0 + c0 * 8;
      const float* p = xin + eoff;
      f32x4 f0 = *(const f32x4*)p;
      f32x4 f1 = *(const f32x4*)(p + 4);
      u16x8 t;
#pragma unroll
      for (int e = 0; e < 4; ++e) { t[e] = f2bf(f0[e]); t[e + 4] = f2bf(f1[e]); }
      sx[i] = t;
      sw[i] = *(const u16x8*)(w0t + (size_t)r * 1024 + k0 + c0 * 8);
    }
  };

  f32x4 acc[2][4] = {};
  preload(0);

  // ---- GEMM0: h = x @ W0, K=1024, 16 slabs of BK=64, single-buffer ----
  for (int s = 0; s < 16; ++s) {
    __syncthreads();                       // prev slab fully consumed
#pragma unroll
    for (int i = 0; i < 2; ++i) {
      int r = (i == 0) ? r0 : r1;
      int p = c0 ^ (r & 7);                // physical chunk (swizzle)
      *(u16x8*)(xs  + r * 128 + p * 16) = sx[i];
      *(u16x8*)(wsm + r * 128 + p * 16) = sw[i];
    }
    __syncthreads();                       // slab s visible
    if (s < 15) preload((s + 1) * 64);     // overlap with MFMA below
#pragma unroll
    for (int kk = 0; kk < 2; ++kk) {
      int ph = ((kk * 4 + quad) ^ (lane & 7)) << 4;
      bf16x8 a[2], b[4];
#pragma unroll
      for (int rh = 0; rh < 2; ++rh)
        a[rh] = *(const bf16x8*)(xs + (m_base + rh * 16 + lane16) * 128 + ph);
#pragma unroll
      for (int nt = 0; nt < 4; ++nt)
        b[nt] = *(const bf16x8*)(wsm + (n_base + nt * 16 + lane16) * 128 + ph);
#pragma unroll
      for (int rh = 0; rh < 2; ++rh)
#pragma unroll
        for (int nt = 0; nt < 4; ++nt)
          acc[rh][nt] = __builtin_amdgcn_mfma_f32_16x16x32_bf16(
              a[rh], b[nt], acc[rh][nt], 0, 0, 0);
    }
  }
  __syncthreads();

  // ---- scatter h+b0 -> hns (C-layout: col=lane16, row=quad*4+reg) ----
#pragma unroll
  for (int rh = 0; rh < 2; ++rh)
#pragma unroll
    for (int nt = 0; nt < 4; ++nt) {
      int col = n_base + nt * 16 + lane16;
#pragma unroll
      for (int r = 0; r < 4; ++r) {
        int row = m_base + rh * 16 + quad * 4 + r;
        *(u16*)(hns + hoff(row, col)) = f2bf(acc[rh][nt][r] + b0v[nt]);
      }
    }
  __syncthreads();

  // ---- rmsnorm over H=128: 4 threads/row ----
  {
    int r = tid >> 2, qq = tid & 3;
    u16x8 vals[4];
    float ss = 0.f;
#pragma unroll
    for (int j = 0; j < 4; ++j) {
      int c = qq * 4 + j;
      vals[j] = *(const u16x8*)(hns + r * 256 + ((c ^ (r & 7)) << 4));
#pragma unroll
      for (int e = 0; e < 8; ++e) { float f = bf2f(vals[j][e]); ss += f * f; }
    }
    ss += __shfl_xor(ss, 1);
    ss += __shfl_xor(ss, 2);
    float scale = rsqrtf(ss * (1.f / 128.f) + 1e-6f);
#pragma unroll
    for (int j = 0; j < 4; ++j) {
      u16x8 o;
#pragma unroll
      for (int e = 0; e < 8; ++e) o[e] = f2bf(bf2f(vals[j][e]) * scale);
      int c = qq * 4 + j;
      *(u16x8*)(hns + r * 256 + ((c ^ (r & 7)) << 4)) = o;
    }
  }
  __syncthreads();

  // ---- GEMM1: h1 = sigmoid(hn @ W1 + b1) + hn -> h1s ----
  f32x4 acc1[2][4] = {};
#pragma unroll
  for (int kk = 0; kk < 4; ++kk) {
    int ph = ((kk * 4 + quad) ^ (lane & 7)) << 4;
    bf16x8 a[2], b[4];
#pragma unroll
    for (int rh = 0; rh < 2; ++rh)
      a[rh] = *(const bf16x8*)(hns + (m_base + rh * 16 + lane16) * 256 + ph);
#pragma unroll
    for (int nt = 0; nt < 4; ++nt)
      b[nt] = *(const bf16x8*)(w1t + (size_t)(n_base + nt * 16 + lane16) * 128 +
                               kk * 32 + quad * 8);
#pragma unroll
    for (int rh = 0; rh < 2; ++rh)
#pragma unroll
      for (int nt = 0; nt < 4; ++nt)
        acc1[rh][nt] = __builtin_amdgcn_mfma_f32_16x16x32_bf16(
            a[rh], b[nt], acc1[rh][nt], 0, 0, 0);
  }
#pragma unroll
  for (int rh = 0; rh < 2; ++rh)
#pragma unroll
    for (int nt = 0; nt < 4; ++nt) {
      int col = n_base + nt * 16 + lane16;
#pragma unroll
      for (int r = 0; r < 4; ++r) {
        int row = m_base + rh * 16 + quad * 4 + r;
        int o = hoff(row, col);
        float hn = bf2f(*(const u16*)(hns + o));
        float v = acc1[rh][nt][r] + b1v[nt];
        *(u16*)(h1s + o) = f2bf(hn + 1.f / (1.f + __expf(-v)));
      }
    }
  __syncthreads();

  // ---- GEMM2: out = relu(h1 @ W2 + b2) + h1, fused fp32 store ----
  f32x4 acc2[2][4] = {};
#pragma unroll
  for (int kk = 0; kk < 4; ++kk) {
    int ph = ((kk * 4 + quad) ^ (lane & 7)) << 4;
    bf16x8 a[2], b[4];
#pragma unroll
    for (int rh = 0; rh < 2; ++rh)
      a[rh] = *(const bf16x8*)(h1s + (m_base + rh * 16 + lane16) * 256 + ph);
#pragma unroll
    for (int nt = 0; nt < 4; ++nt)
      b[nt] = *(const bf16x8*)(w2t + (size_t)(n_base + nt * 16 + lane16) * 128 +
                               kk * 32 + quad * 8);
#pragma unroll
    for (int rh = 0; rh < 2; ++rh)
#pragma unroll
      for (int nt = 0; nt < 4; ++nt)
        acc2[rh][nt] = __builtin_amdgcn_mfma_f32_16x16x32_bf16(
            a[rh], b[nt], acc2[rh][nt], 0, 0, 0);
  }
#pragma unroll
  for (int rh = 0; rh < 2; ++rh)
#pragma unroll
    for (int nt = 0; nt < 4; ++nt) {
      int col = n_base + nt * 16 + lane16;
#pragma unroll
      for (int r = 0; r < 4; ++r) {
        int row = m_base + rh * 16 + quad * 4 + r;
        float h1v = bf2f(*(const u16*)(h1s + hoff(row, col)));
        float v = acc2[rh][nt][r] + b2v[nt];
        float res = h1v + fmaxf(v, 0.f);
        outv[(size_t)(row0 + row) * 128 + col] = res;
      }
    }
}

// ---------------------------------------------------------------------------
extern "C" void kernel_launch(void* const* d_in, const int* in_sizes, int n_in,
                              void* d_out, int out_size, void* d_ws, size_t ws_size,
                              hipStream_t stream) {
  const float* x  = (const float*)d_in[0];
  const float* W0 = (const float*)d_in[1];
  const float* b0 = (const float*)d_in[2];
  const float* W1 = (const float*)d_in[3];
  const float* b1 = (const float*)d_in[4];
  const float* W2 = (const float*)d_in[5];
  const float* b2 = (const float*)d_in[6];
  char* wsb = (char*)d_ws;

  prep_kernel<<<161, 256, 0, stream>>>(W0, W1, W2, b0, b1, b2, wsb);
  fused_kernel<<<256, 512, 0, stream>>>(x, wsb, (float*)d_out);
}